// Round 1
// 177.226 us; speedup vs baseline: 1.2514x; 1.2514x over previous
//
#include <hip/hip_runtime.h>
#include <stdint.h>

typedef __bf16 bf16;
typedef __bf16 bf16x8 __attribute__((ext_vector_type(8)));
typedef float  f32x4  __attribute__((ext_vector_type(4)));

#define NSEQ 4096
#define NROWS 16384
#define CHUNK 32
#define NCHUNKS_B 128
#define NCHUNKS 512
#define SEGLEN 16
#define NSEG 8
#define YSTRIDE 516

__device__ __forceinline__ float bf2f(uint16_t u){
    uint32_t w = ((uint32_t)u) << 16;
    return __builtin_bit_cast(float, w);
}
__device__ __forceinline__ uint32_t pack2(float a, float b){
    uint16_t ua = __builtin_bit_cast(uint16_t, (bf16)a);
    uint16_t ub = __builtin_bit_cast(uint16_t, (bf16)b);
    return ((uint32_t)ub << 16) | (uint32_t)ua;
}
__device__ __forceinline__ uint4 cvt8(const float* p){
    float4 lo = *(const float4*)p;
    float4 hi = *(const float4*)(p + 4);
    uint4 r;
    r.x = pack2(lo.x, lo.y); r.y = pack2(lo.z, lo.w);
    r.z = pack2(hi.x, hi.y); r.w = pack2(hi.z, hi.w);
    return r;
}
__device__ __forceinline__ float rd_any(const void* p, long idx, int f){
    return f ? ((const float*)p)[idx] : (float)((const bf16*)p)[idx];
}
// async global->LDS, 16B per lane; ldsp must be wave-uniform (dest = ldsp + lane*16)
__device__ __forceinline__ void cp16(const void* g, void* l){
    __builtin_amdgcn_global_load_lds((const __attribute__((address_space(1))) void*)g,
                                     (__attribute__((address_space(3))) void*)l,
                                     16, 0, 0);
}

// ---- prep: dtype detect + canonicalize small tensors + decay tables ----
// grid = 12 blocks; every block recomputes the flag independently (deterministic)
__global__ __launch_bounds__(256) void prep_kernel(const uint32_t* __restrict__ xw,
                                                   const void* We, const void* Ws,
                                                   const void* op, const void* g, const void* b,
                                                   bf16* __restrict__ Wt_es,
                                                   float* __restrict__ g_c, float* __restrict__ b_c,
                                                   float* __restrict__ o_buf, float* __restrict__ oL_buf,
                                                   float* __restrict__ lsL_buf, float* __restrict__ oL16_buf,
                                                   int* __restrict__ flag_g){
    __shared__ int cnt[256];
    int tid = threadIdx.x;
    int c = 0;
    #pragma unroll
    for (int j = 0; j < 4; ++j){
        uint32_t w = xw[tid*4 + j];
        uint32_t e = (w >> 7) & 0xFF;
        c += (e >= 110 && e <= 140) ? 1 : 0;
    }
    cnt[tid] = c; __syncthreads();
    for (int s = 128; s; s >>= 1){
        if (tid < s) cnt[tid] += cnt[tid + s];
        __syncthreads();
    }
    int f = (cnt[0] < 512) ? 1 : 0;
    int blk = blockIdx.x;
    if (blk == 0 && tid == 0) flag_g[0] = f;
    if (blk < 8){
        // Wt_es[n][k]: n<8 -> We[k*8+n], else Ws[k*8+n-8]; 1024 entries per block
        for (int i = tid; i < 1024; i += 256){
            int gi = blk*1024 + i;
            int n = gi >> 9, k = gi & 511;
            float v = (n < 8) ? rd_any(We, (long)k*8 + n, f)
                              : rd_any(Ws, (long)k*8 + (n-8), f);
            Wt_es[gi] = (bf16)v;
        }
    } else {
        int base = (blk - 8) * 1024;
        for (int i = tid; i < 1024; i += 256){
            int gi = base + i;
            float x = rd_any(op, gi, f);
            float ls = (x < 0.f) ? (x - log1pf(expf(x))) : (0.f - log1pf(expf(-x)));
            o_buf[gi]    = expf(ls * (1.0f/16.0f));       // o = sigmoid^(1/16)
            oL_buf[gi]   = expf(ls * 2.0f);               // o^32
            lsL_buf[gi]  = ls * 2.0f;                     // log(o^32)
            oL16_buf[gi] = expf(ls * 32.0f);              // o^512
        }
    }
    if (blk == 0){
        for (int i = tid; i < 512; i += 256){
            g_c[i] = rd_any(g, i, f);
            b_c[i] = rd_any(b, i, f);
        }
    }
}

// ---- transpose both 512x512 weights -> bf16 B^T layout ----
__global__ __launch_bounds__(256) void transpose2(const void* __restrict__ Wi,
                                                  const void* __restrict__ Wo,
                                                  bf16* __restrict__ Wt_i,
                                                  bf16* __restrict__ Wt_o,
                                                  const int* __restrict__ flag){
    __shared__ bf16 T[64][65];
    int mat = blockIdx.x >> 6;
    int t   = blockIdx.x & 63;
    int k0  = (t >> 3) * 64, n0 = (t & 7) * 64;
    const void* in = mat ? Wo : Wi;
    bf16* out = mat ? Wt_o : Wt_i;
    int f = *flag;
    int tid = threadIdx.x;
    #pragma unroll
    for (int e = 0; e < 16; ++e){
        int idx = e*256 + tid;
        int r = idx >> 6, c = idx & 63;
        T[c][r] = (bf16)rd_any(in, (long)(k0 + r)*512 + n0 + c, f);
    }
    __syncthreads();
    #pragma unroll
    for (int e = 0; e < 16; ++e){
        int idx = e*256 + tid;
        int rn = idx >> 6, ck = idx & 63;
        out[(long)(n0 + rn)*512 + k0 + ck] = T[rn][ck];
    }
}

// ---- GEMM: C(MxN) = A(MxK) * Bt(NxK)^T, bf16 MFMA, async LDS staging ----
// Optional fused e/s projection (Wes non-null): ntile==0, wc==0 waves also
// accumulate A-tile x Wt_es (16 cols) from the already-staged LDS fragments.
__global__ __launch_bounds__(256) void gemm_bt(const void* __restrict__ Avoid,
                                               const bf16* __restrict__ Bt,
                                               void* __restrict__ Cvoid,
                                               int M, int N, int Kd,
                                               const int* __restrict__ aflag,
                                               const int* __restrict__ cflag,
                                               const bf16* __restrict__ Wes,
                                               float* __restrict__ e_out,
                                               float* __restrict__ s_out){
    __shared__ __align__(16) bf16 As[128*32];
    __shared__ __align__(16) bf16 Bs[128*32];
    const int tid  = threadIdx.x;
    const int lane = tid & 63;
    const int wave = tid >> 6;
    const int ntiles = N >> 7;
    // XCD-bijective swizzle: colocate the ntile-blocks of one mtile on one XCD
    // so the shared A panel is an L2 hit, not 4x cross-XCD refetch. 512%8==0.
    int bid = blockIdx.x;
    {
        const int q = gridDim.x >> 3;
        bid = (bid & 7) * q + (bid >> 3);
    }
    const int mtile = bid / ntiles;
    const int ntile = bid - mtile*ntiles;
    const int m0 = mtile << 7, n0 = ntile << 7;
    const int wr = (wave >> 1) << 6;
    const int wc = (wave & 1) << 6;
    const int lrow = lane & 15;
    const int quad = lane >> 4;
    const int fa = aflag ? *aflag : 0;
    const bool do_es = (Wes != nullptr) && (ntile == 0) && (wc == 0);

    f32x4 acc[4][4] = {};
    f32x4 acc_es[4] = {};

    const int sr = tid >> 2;              // staging row 0..63
    const int sk = (tid & 3) << 3;        // k offset 0/8/16/24
    const bf16*  Ag  = (const bf16*) Avoid + (long)(m0 + sr)*Kd + sk;
    const float* Agf = (const float*)Avoid + (long)(m0 + sr)*Kd + sk;
    const bf16*  Bg  = Bt + (long)(n0 + sr)*Kd + sk;

    for (int k0 = 0; k0 < Kd; k0 += 32){
        uint4 a0, a1;
        if (fa){
            a0 = cvt8(Agf + k0);
            a1 = cvt8(Agf + (long)64*Kd + k0);
        }
        if (k0) __syncthreads();          // prev iter's LDS reads done
        if (fa){
            *(uint4*)&As[tid*8]        = a0;
            *(uint4*)&As[2048 + tid*8] = a1;
        } else {
            cp16(Ag + k0,                &As[(size_t)wave*512]);
            cp16(Ag + (long)64*Kd + k0,  &As[2048 + (size_t)wave*512]);
        }
        cp16(Bg + k0,                &Bs[(size_t)wave*512]);
        cp16(Bg + (long)64*Kd + k0,  &Bs[2048 + (size_t)wave*512]);
        __syncthreads();                  // drains vmcnt+lds before use

        bf16x8 af[4], bfr[4];
        #pragma unroll
        for (int i = 0; i < 4; ++i)
            af[i]  = *(const bf16x8*)&As[(wr + i*16 + lrow)*32 + quad*8];
        #pragma unroll
        for (int j = 0; j < 4; ++j)
            bfr[j] = *(const bf16x8*)&Bs[(wc + j*16 + lrow)*32 + quad*8];
        #pragma unroll
        for (int i = 0; i < 4; ++i)
            #pragma unroll
            for (int j = 0; j < 4; ++j)
                acc[i][j] = __builtin_amdgcn_mfma_f32_16x16x32_bf16(af[i], bfr[j], acc[i][j], 0, 0, 0);
        if (do_es){
            bf16x8 be = *(const bf16x8*)(Wes + (long)lrow*512 + k0 + quad*8);
            #pragma unroll
            for (int i = 0; i < 4; ++i)
                acc_es[i] = __builtin_amdgcn_mfma_f32_16x16x32_bf16(af[i], be, acc_es[i], 0, 0, 0);
        }
    }

    const int fc = cflag ? *cflag : 0;
    // C/D layout: col = lane&15, row = quad*4 + reg
    if (fc){
        float* Cf = (float*)Cvoid;
        #pragma unroll
        for (int i = 0; i < 4; ++i){
            int gr = m0 + wr + i*16 + quad*4;
            #pragma unroll
            for (int j = 0; j < 4; ++j){
                int gc = n0 + wc + j*16 + lrow;
                #pragma unroll
                for (int r = 0; r < 4; ++r)
                    Cf[(long)(gr + r)*N + gc] = acc[i][j][r];
            }
        }
    } else {
        bf16* Cb = (bf16*)Cvoid;
        #pragma unroll
        for (int i = 0; i < 4; ++i){
            int gr = m0 + wr + i*16 + quad*4;
            #pragma unroll
            for (int j = 0; j < 4; ++j){
                int gc = n0 + wc + j*16 + lrow;
                #pragma unroll
                for (int r = 0; r < 4; ++r)
                    Cb[(long)(gr + r)*N + gc] = (bf16)acc[i][j][r];
            }
        }
    }
    if (do_es){
        // D: col=lane&15 (0..7 -> e, 8..15 -> s), row = quad*4 + reg
        float* eo = (lrow < 8) ? e_out : s_out;
        int col = lrow & 7;
        #pragma unroll
        for (int i = 0; i < 4; ++i){
            int gr = m0 + wr + i*16 + quad*4;
            #pragma unroll
            for (int r = 0; r < 4; ++r)
                eo[(long)(gr + r)*8 + col] = acc_es[i][r];
        }
    }
}

// ---- pass A: per-chunk local state (from zero), 32 steps ----
__global__ __launch_bounds__(256) void passA(const bf16* __restrict__ i_buf,
                                             const float* __restrict__ e_buf,
                                             const float* __restrict__ o_buf,
                                             float* __restrict__ Ams){
    int c  = blockIdx.x;
    int b  = c >> 7;
    int t0 = (c & 127) * CHUNK;
    int tid = threadIdx.x;
    __shared__ float eS[CHUNK*8];
    eS[tid] = e_buf[((long)(b*NSEQ + t0))*8 + tid];
    __syncthreads();
    int d0 = tid*2;
    float o0[8], o1[8], m0[8], m1[8];
    #pragma unroll
    for (int k = 0; k < 8; ++k){
        o0[k] = o_buf[k*512 + d0]; o1[k] = o_buf[k*512 + d0 + 1];
        m0[k] = 0.f; m1[k] = 0.f;
    }
    const bf16* ip = i_buf + (long)(b*NSEQ + t0)*512 + d0;
    for (int t = 0; t < CHUNK; ++t){
        uint32_t iv = *(const uint32_t*)(ip + (long)t*512);
        float i0 = bf2f((uint16_t)iv), i1 = bf2f((uint16_t)(iv >> 16));
        #pragma unroll
        for (int k = 0; k < 8; ++k){
            float ek = eS[t*8 + k];
            m0[k] = o0[k]*m0[k] + ek*i0;
            m1[k] = o1[k]*m1[k] + ek*i1;
        }
    }
    float* Ac = Ams + (long)c*4096;
    #pragma unroll
    for (int k = 0; k < 8; ++k){
        float2 v; v.x = m0[k]; v.y = m1[k];
        *(float2*)&Ac[k*512 + d0] = v;
    }
}

// ---- B1: in-place local prefix within each 16-chunk segment + totals ----
__global__ __launch_bounds__(256) void passB1(float* __restrict__ Ams,
                                              const float* __restrict__ oL_buf,
                                              float* __restrict__ Tbuf){
    int bs  = blockIdx.x >> 4;                       // b*8+seg, 0..31
    int b   = bs >> 3, seg = bs & 7;
    int idx = (blockIdx.x & 15)*256 + threadIdx.x;   // 0..4095
    float oL = oL_buf[idx];
    float m = 0.f;
    float* Mb = Ams + ((long)b*NCHUNKS_B + seg*SEGLEN)*4096 + idx;
    #pragma unroll 4
    for (int cc = 0; cc < SEGLEN; ++cc){
        float a = Mb[(long)cc*4096];
        Mb[(long)cc*4096] = m;
        m = oL*m + a;
    }
    Tbuf[(long)bs*4096 + idx] = m;
}

// ---- B2: scan segment totals in registers -> segment-start states ----
__global__ __launch_bounds__(256) void passB2(float* __restrict__ Tbuf,
                                              const float* __restrict__ oL16_buf){
    int b   = blockIdx.x >> 4;
    int idx = (blockIdx.x & 15)*256 + threadIdx.x;
    float oL16 = oL16_buf[idx];
    float t[NSEG];
    #pragma unroll
    for (int s = 0; s < NSEG; ++s)
        t[s] = Tbuf[((long)b*NSEG + s)*4096 + idx];
    float m = 0.f;
    #pragma unroll
    for (int s = 0; s < NSEG; ++s){
        Tbuf[((long)b*NSEG + s)*4096 + idx] = m;
        m = oL16*m + t[s];
    }
}

// ---- pass C: replay chunk (with segment fixup) + fused LayerNorm ----
// y buffered in LDS (fp32), per-row stats in-block, normalized bf16 overwrite.
__global__ __launch_bounds__(256) void passC(bf16* __restrict__ iy,
                                             const float* __restrict__ e_buf,
                                             const float* __restrict__ s_buf,
                                             const float* __restrict__ o_buf,
                                             const float* __restrict__ Ploc,
                                             const float* __restrict__ Mseg,
                                             const float* __restrict__ lsL_buf,
                                             const float* __restrict__ g_c,
                                             const float* __restrict__ b_c){
    int c  = blockIdx.x;
    int b  = c >> 7;
    int cI = c & 127;
    int seg = cI >> 4;
    float fj = (float)(cI & 15);
    int t0 = cI * CHUNK;
    int tid = threadIdx.x;
    __shared__ float eS[CHUNK*8], sS[CHUNK*8];
    __shared__ float muS[CHUNK], rS[CHUNK];
    __shared__ __align__(16) float yS[CHUNK][YSTRIDE];   // 516 stride: de-bank rows
    eS[tid] = e_buf[((long)(b*NSEQ + t0))*8 + tid];
    sS[tid] = s_buf[((long)(b*NSEQ + t0))*8 + tid];
    __syncthreads();
    int d0 = tid*2;
    float o0[8], o1[8], m0[8], m1[8];
    const float* P0 = Ploc + (long)c*4096;
    const float* Ms = Mseg + ((long)b*NSEG + seg)*4096;
    #pragma unroll
    for (int k = 0; k < 8; ++k){
        int i0 = k*512 + d0;
        o0[k] = o_buf[i0]; o1[k] = o_buf[i0 + 1];
        m0[k] = P0[i0]   + __expf(lsL_buf[i0]  *fj)*Ms[i0];
        m1[k] = P0[i0+1] + __expf(lsL_buf[i0+1]*fj)*Ms[i0+1];
    }
    bf16* ip = iy + (long)(b*NSEQ + t0)*512 + d0;
    for (int t = 0; t < CHUNK; ++t){
        uint32_t iv = *(const uint32_t*)(ip + (long)t*512);
        float i0 = bf2f((uint16_t)iv), i1 = bf2f((uint16_t)(iv >> 16));
        float y0 = 0.f, y1 = 0.f;
        #pragma unroll
        for (int k = 0; k < 8; ++k){
            float ek = eS[t*8 + k], sk = sS[t*8 + k];
            m0[k] = o0[k]*m0[k] + ek*i0;
            m1[k] = o1[k]*m1[k] + ek*i1;
            y0 += sk*m0[k];
            y1 += sk*m1[k];
        }
        float2 yv; yv.x = y0; yv.y = y1;
        *(float2*)&yS[t][d0] = yv;
    }
    __syncthreads();
    // per-row stats: 8 threads per row, 64 elems each, shuffle-combine
    {
        int row = tid >> 3, sub = tid & 7;
        const float4* yr = (const float4*)&yS[row][sub*64];
        float s = 0.f, s2 = 0.f;
        #pragma unroll
        for (int j = 0; j < 16; ++j){
            float4 v = yr[j];
            s  += v.x + v.y + v.z + v.w;
            s2 += v.x*v.x + v.y*v.y + v.z*v.z + v.w*v.w;
        }
        s += __shfl_xor(s, 1); s2 += __shfl_xor(s2, 1);
        s += __shfl_xor(s, 2); s2 += __shfl_xor(s2, 2);
        s += __shfl_xor(s, 4); s2 += __shfl_xor(s2, 4);
        if (sub == 0){
            float mu  = s * (1.f/512.f);
            float var = s2 * (1.f/512.f) - mu*mu;
            muS[row] = mu;
            rS[row]  = rsqrtf(var + 1e-5f);
        }
    }
    __syncthreads();
    float g0 = g_c[d0], g1 = g_c[d0+1];
    float bb0 = b_c[d0], bb1 = b_c[d0+1];
    for (int t = 0; t < CHUNK; ++t){
        float mu = muS[t], r = rS[t];
        float2 yv = *(const float2*)&yS[t][d0];
        float a0 = (yv.x - mu)*r*g0 + bb0;
        float a1 = (yv.y - mu)*r*g1 + bb1;
        *(uint32_t*)(ip + (long)t*512) = pack2(a0, a1);
    }
}

extern "C" void kernel_launch(void* const* d_in, const int* in_sizes, int n_in,
                              void* d_out, int out_size, void* d_ws, size_t ws_size,
                              hipStream_t stream){
    const void* x    = d_in[0];
    const void* W_i  = d_in[1];
    const void* W_e  = d_in[2];
    const void* W_s  = d_in[3];
    const void* o_p  = d_in[4];
    const void* gmm  = d_in[5];
    const void* bta  = d_in[6];
    const void* W_o  = d_in[7];

    char* ws = (char*)d_ws;
    bf16*  Wt_i   = (bf16*) (ws + 0);          // 512 KB (dead after gemm1)
    float* Tbuf   = (float*)(ws + 0);          // aliased: B1 totals / B2 seg-starts
    bf16*  Wt_o   = (bf16*) (ws + 524288);     // 512 KB
    bf16*  iy_buf = (bf16*) (ws + 1048576);    // 16 MB (i, then y in-place)
    float* e_buf  = (float*)(ws + 17825792);   // 512 KB
    float* s_buf  = (float*)(ws + 18350080);   // 512 KB
    float* o_buf  = (float*)(ws + 18874368);   // 16 KB
    float* oL_buf = (float*)(ws + 18890752);   // 16 KB
    float* lsL    = (float*)(ws + 18907136);   // 16 KB
    float* oL16   = (float*)(ws + 18923520);   // 16 KB
    float* Ams    = (float*)(ws + 18939904);   // 8 MB (A, then local prefixes)
    bf16*  Wt_es  = (bf16*) (ws + 27328512);   // 16 KB
    float* g_c    = (float*)(ws + 27344896);   // 2 KB
    float* b_c    = (float*)(ws + 27346944);   // 2 KB
    int*   flag   = (int*)  (ws + 27348992);   // 256 B  (total ~26.1 MB)

    prep_kernel<<<12,   256, 0, stream>>>((const uint32_t*)x, W_e, W_s, o_p, gmm, bta,
                                          Wt_es, g_c, b_c, o_buf, oL_buf, lsL, oL16, flag);
    transpose2 <<<128,  256, 0, stream>>>(W_i, W_o, Wt_i, Wt_o, flag);
    gemm_bt    <<<512,  256, 0, stream>>>(x, Wt_i, iy_buf, NROWS, 512, 512, flag, nullptr,
                                          Wt_es, e_buf, s_buf);
    passA      <<<NCHUNKS, 256, 0, stream>>>(iy_buf, e_buf, o_buf, Ams);
    passB1     <<<512,  256, 0, stream>>>(Ams, oL_buf, Tbuf);
    passB2     <<<64,   256, 0, stream>>>(Tbuf, oL16);
    passC      <<<NCHUNKS, 256, 0, stream>>>(iy_buf, e_buf, s_buf, o_buf, Ams, Tbuf, lsL,
                                             g_c, b_c);
    gemm_bt    <<<512,  256, 0, stream>>>(iy_buf, Wt_o, d_out, NROWS, 512, 512, nullptr, flag,
                                          nullptr, nullptr, nullptr);
}